// Round 4
// baseline (295.522 us; speedup 1.0000x reference)
//
#include <hip/hip_runtime.h>

// Graph conv x2 (same graph both layers):
//   L1: agg1 = segment_mean(feat[src]->dst); h = relu(agg1@W1+b1)
//   L2: agg2 = segment_mean(h[src]->dst);    out = agg2@W2+b2
// Fused per node: g = relu(mean@W1+b1)@W2 (3 floats) before 2nd aggregation.
//
// Ladder: R0 global-atomic scatter 1594us -> R1 per-node slot table 341us
// (placement atomics cap ~22G ops/s) -> R2 bucketed LDS aggregation 251us
// (k_l1 latency-bound at 22% occupancy, grid=256). R3: 782 buckets of 128
// nodes (shift/mask indexing), 32B-padded feature rows (aligned float4x2
// gathers), uint4 packed-edge reads.

#define IN_F 6
#define HID_F 32
#define OUT_F 3

#define NPB 128          // nodes per bucket (power of two)
#define NPB_SHIFT 7
#define MAXB 1024        // max buckets supported by scatter LDS histograms
#define CAPB 4864        // per-bucket edge cap (mean 4093, sd ~64 -> +12 sigma)
#define SRC_BITS 17
#define SRC_MASK ((1u << SRC_BITS) - 1)

// ---------------- pad 24B feature rows to 32B -------------------------------
__global__ void k_pad(const float* __restrict__ feat, float4* __restrict__ feat8, int nN) {
    int n = blockIdx.x * blockDim.x + threadIdx.x;
    if (n >= nN) return;
    const float* f = feat + (size_t)n * IN_F;
    float2 f01 = *reinterpret_cast<const float2*>(f + 0);
    float2 f23 = *reinterpret_cast<const float2*>(f + 2);
    float2 f45 = *reinterpret_cast<const float2*>(f + 4);
    feat8[2 * n + 0] = make_float4(f01.x, f01.y, f23.x, f23.y);
    feat8[2 * n + 1] = make_float4(f45.x, f45.y, 0.0f, 0.0f);
}

// ---------------- bucketize edges by dst range ------------------------------
__global__ void k_scatter(const int* __restrict__ src, const int* __restrict__ dst,
                          int nB, int* __restrict__ cursor_g,
                          unsigned* __restrict__ packed, int nE) {
    __shared__ int hist[MAXB];
    __shared__ int basech[MAXB];
    int per = (nE + gridDim.x - 1) / gridDim.x;
    int e0 = blockIdx.x * per;
    int e1 = min(e0 + per, nE);

    for (int i = threadIdx.x; i < nB; i += blockDim.x) hist[i] = 0;
    __syncthreads();

    for (int e = e0 + threadIdx.x; e < e1; e += blockDim.x)
        atomicAdd(&hist[dst[e] >> NPB_SHIFT], 1);
    __syncthreads();

    for (int b = threadIdx.x; b < nB; b += blockDim.x) {
        int h = hist[b];
        basech[b] = h ? atomicAdd(&cursor_g[b], h) : 0;  // global reserve
        hist[b] = 0;                                     // reuse as place cursor
    }
    __syncthreads();

    for (int e = e0 + threadIdx.x; e < e1; e += blockDim.x) {
        int d = dst[e];
        int b = d >> NPB_SHIFT;
        unsigned dl = (unsigned)(d & (NPB - 1));
        int pos = basech[b] + atomicAdd(&hist[b], 1);
        if (pos < CAPB)
            packed[(size_t)b * CAPB + pos] = (dl << SRC_BITS) | (unsigned)src[e];
    }
}

// ---------------- layer 1: LDS mean-aggregate + fused MLP -------------------
__global__ void k_l1(const unsigned* __restrict__ packed, const int* __restrict__ cursor_g,
                     const float4* __restrict__ feat8,
                     const float* __restrict__ W1, const float* __restrict__ b1,
                     const float* __restrict__ W2,
                     float4* __restrict__ g4, float* __restrict__ deg, int nN) {
    __shared__ float sW1[IN_F * HID_F];   // [i][j], stride HID_F
    __shared__ float sb1[HID_F];
    __shared__ float sW2[HID_F * OUT_F];  // [j][k], stride OUT_F
    __shared__ float acc[NPB * 7];        // stride 7: coprime with 32 banks
    __shared__ int   cnt[NPB];

    for (int i = threadIdx.x; i < IN_F * HID_F; i += blockDim.x)  sW1[i] = W1[i];
    for (int i = threadIdx.x; i < HID_F; i += blockDim.x)         sb1[i] = b1[i];
    for (int i = threadIdx.x; i < HID_F * OUT_F; i += blockDim.x) sW2[i] = W2[i];
    for (int i = threadIdx.x; i < NPB * 7; i += blockDim.x)       acc[i] = 0.0f;
    for (int i = threadIdx.x; i < NPB; i += blockDim.x)           cnt[i] = 0;
    __syncthreads();

    int b  = blockIdx.x;
    int n0 = b << NPB_SHIFT;
    int ecnt = min(cursor_g[b], CAPB);
    const unsigned* ep = packed + (size_t)b * CAPB;

#define PROC(P)                                                            \
    do {                                                                   \
        unsigned s = (P) & SRC_MASK;                                       \
        int dl = (int)((P) >> SRC_BITS);                                   \
        float4 fa = feat8[2 * (size_t)s + 0];                              \
        float4 fb = feat8[2 * (size_t)s + 1];                              \
        float* a = acc + dl * 7;                                           \
        atomicAdd(a + 0, fa.x); atomicAdd(a + 1, fa.y);                    \
        atomicAdd(a + 2, fa.z); atomicAdd(a + 3, fa.w);                    \
        atomicAdd(a + 4, fb.x); atomicAdd(a + 5, fb.y);                    \
        atomicAdd(&cnt[dl], 1);                                            \
    } while (0)

    const uint4* ep4 = reinterpret_cast<const uint4*>(ep);  // bucket base 16B-aligned
    int nq = ecnt >> 2;
    for (int i = threadIdx.x; i < nq; i += blockDim.x) {
        uint4 pp = ep4[i];
        PROC(pp.x); PROC(pp.y); PROC(pp.z); PROC(pp.w);
    }
    for (int i = (nq << 2) + threadIdx.x; i < ecnt; i += blockDim.x) PROC(ep[i]);
#undef PROC
    __syncthreads();

    int nloc = min(NPB, nN - n0); if (nloc < 0) nloc = 0;
    for (int t = threadIdx.x; t < nloc; t += blockDim.x) {
        int c = cnt[t];
        float inv = 1.0f / fmaxf((float)c, 1.0f);
        float a0 = acc[t * 7 + 0] * inv, a1 = acc[t * 7 + 1] * inv;
        float a2 = acc[t * 7 + 2] * inv, a3 = acc[t * 7 + 3] * inv;
        float a4 = acc[t * 7 + 4] * inv, a5 = acc[t * 7 + 5] * inv;
        float g0 = 0.f, g1 = 0.f, g2 = 0.f;
#pragma unroll
        for (int j = 0; j < HID_F; ++j) {
            float t1 = sb1[j];
            t1 = fmaf(a0, sW1[0 * HID_F + j], t1);
            t1 = fmaf(a1, sW1[1 * HID_F + j], t1);
            t1 = fmaf(a2, sW1[2 * HID_F + j], t1);
            t1 = fmaf(a3, sW1[3 * HID_F + j], t1);
            t1 = fmaf(a4, sW1[4 * HID_F + j], t1);
            t1 = fmaf(a5, sW1[5 * HID_F + j], t1);
            t1 = fmaxf(t1, 0.0f);  // relu
            g0 = fmaf(t1, sW2[j * OUT_F + 0], g0);
            g1 = fmaf(t1, sW2[j * OUT_F + 1], g1);
            g2 = fmaf(t1, sW2[j * OUT_F + 2], g2);
        }
        g4[n0 + t]  = make_float4(g0, g1, g2, 0.0f);
        deg[n0 + t] = (float)c;
    }
}

// ---------------- layer 2: LDS mean-aggregate of g + bias -------------------
__global__ void k_l2(const unsigned* __restrict__ packed, const int* __restrict__ cursor_g,
                     const float4* __restrict__ g4, const float* __restrict__ deg,
                     const float* __restrict__ b2,
                     float* __restrict__ out, int nN) {
    __shared__ float acc2[NPB * 5];   // stride 5: coprime with 32 banks
    for (int i = threadIdx.x; i < NPB * 5; i += blockDim.x) acc2[i] = 0.0f;
    __syncthreads();

    int b  = blockIdx.x;
    int n0 = b << NPB_SHIFT;
    int ecnt = min(cursor_g[b], CAPB);
    const unsigned* ep = packed + (size_t)b * CAPB;

#define PROC2(P)                                                           \
    do {                                                                   \
        unsigned s = (P) & SRC_MASK;                                       \
        int dl = (int)((P) >> SRC_BITS);                                   \
        float4 g = g4[s];                                                  \
        float* a = acc2 + dl * 5;                                          \
        atomicAdd(a + 0, g.x); atomicAdd(a + 1, g.y); atomicAdd(a + 2, g.z); \
    } while (0)

    const uint4* ep4 = reinterpret_cast<const uint4*>(ep);
    int nq = ecnt >> 2;
    for (int i = threadIdx.x; i < nq; i += blockDim.x) {
        uint4 pp = ep4[i];
        PROC2(pp.x); PROC2(pp.y); PROC2(pp.z); PROC2(pp.w);
    }
    for (int i = (nq << 2) + threadIdx.x; i < ecnt; i += blockDim.x) PROC2(ep[i]);
#undef PROC2
    __syncthreads();

    int nloc = min(NPB, nN - n0); if (nloc < 0) nloc = 0;
    float c0 = b2[0], c1 = b2[1], c2 = b2[2];
    for (int t = threadIdx.x; t < nloc; t += blockDim.x) {
        int n = n0 + t;
        float inv = 1.0f / fmaxf(deg[n], 1.0f);
        out[(size_t)n * OUT_F + 0] = acc2[t * 5 + 0] * inv + c0;
        out[(size_t)n * OUT_F + 1] = acc2[t * 5 + 1] * inv + c1;
        out[(size_t)n * OUT_F + 2] = acc2[t * 5 + 2] * inv + c2;
    }
}

// ===================== fallback path (R0, atomic scatter) ===================
__global__ void scatter1(const int* __restrict__ src, const int* __restrict__ dst,
                         const float* __restrict__ feat,
                         float* __restrict__ acc1, float* __restrict__ deg, int nE) {
    int e = blockIdx.x * blockDim.x + threadIdx.x;
    if (e >= nE) return;
    int s = src[e], d = dst[e];
    const float* f = feat + (size_t)s * IN_F;
    float* a = acc1 + (size_t)d * IN_F;
    float2 f01 = *reinterpret_cast<const float2*>(f + 0);
    float2 f23 = *reinterpret_cast<const float2*>(f + 2);
    float2 f45 = *reinterpret_cast<const float2*>(f + 4);
    atomicAdd(a + 0, f01.x); atomicAdd(a + 1, f01.y); atomicAdd(a + 2, f23.x);
    atomicAdd(a + 3, f23.y); atomicAdd(a + 4, f45.x); atomicAdd(a + 5, f45.y);
    atomicAdd(deg + d, 1.0f);
}

__global__ void node_mlp(float* __restrict__ acc1, const float* __restrict__ deg,
                         const float* __restrict__ W1, const float* __restrict__ b1,
                         const float* __restrict__ W2, int nN) {
    __shared__ float sW1[IN_F * HID_F];
    __shared__ float sb1[HID_F];
    __shared__ float sW2[HID_F * OUT_F];
    for (int i = threadIdx.x; i < IN_F * HID_F; i += blockDim.x)  sW1[i] = W1[i];
    for (int i = threadIdx.x; i < HID_F; i += blockDim.x)         sb1[i] = b1[i];
    for (int i = threadIdx.x; i < HID_F * OUT_F; i += blockDim.x) sW2[i] = W2[i];
    __syncthreads();
    int n = blockIdx.x * blockDim.x + threadIdx.x;
    if (n >= nN) return;
    float inv = 1.0f / fmaxf(deg[n], 1.0f);
    float a[IN_F];
    float* row = acc1 + (size_t)n * IN_F;
#pragma unroll
    for (int i = 0; i < IN_F; ++i) a[i] = row[i] * inv;
    float g0 = 0.f, g1 = 0.f, g2 = 0.f;
#pragma unroll
    for (int j = 0; j < HID_F; ++j) {
        float t = sb1[j];
#pragma unroll
        for (int i = 0; i < IN_F; ++i) t = fmaf(a[i], sW1[i * HID_F + j], t);
        t = fmaxf(t, 0.0f);
        g0 = fmaf(t, sW2[j * OUT_F + 0], g0);
        g1 = fmaf(t, sW2[j * OUT_F + 1], g1);
        g2 = fmaf(t, sW2[j * OUT_F + 2], g2);
    }
    row[0] = g0; row[1] = g1; row[2] = g2;
}

__global__ void scatter2(const int* __restrict__ src, const int* __restrict__ dst,
                         const float* __restrict__ g, float* __restrict__ acc2, int nE) {
    int e = blockIdx.x * blockDim.x + threadIdx.x;
    if (e >= nE) return;
    int s = src[e], d = dst[e];
    const float* gs = g + (size_t)s * IN_F;
    float* a = acc2 + (size_t)d * OUT_F;
    float2 g01 = *reinterpret_cast<const float2*>(gs);
    atomicAdd(a + 0, g01.x); atomicAdd(a + 1, g01.y); atomicAdd(a + 2, gs[2]);
}

__global__ void finalize(const float* __restrict__ acc2, const float* __restrict__ deg,
                         const float* __restrict__ b2, float* __restrict__ out, int nN) {
    int n = blockIdx.x * blockDim.x + threadIdx.x;
    if (n >= nN) return;
    float inv = 1.0f / fmaxf(deg[n], 1.0f);
    out[(size_t)n * OUT_F + 0] = acc2[(size_t)n * OUT_F + 0] * inv + b2[0];
    out[(size_t)n * OUT_F + 1] = acc2[(size_t)n * OUT_F + 1] * inv + b2[1];
    out[(size_t)n * OUT_F + 2] = acc2[(size_t)n * OUT_F + 2] * inv + b2[2];
}

// ============================================================================
extern "C" void kernel_launch(void* const* d_in, const int* in_sizes, int n_in,
                              void* d_out, int out_size, void* d_ws, size_t ws_size,
                              hipStream_t stream) {
    const float* feat = (const float*)d_in[0];
    const int*   src  = (const int*)d_in[1];
    const int*   dst  = (const int*)d_in[2];
    const float* W1   = (const float*)d_in[3];
    const float* b1   = (const float*)d_in[4];
    const float* W2   = (const float*)d_in[5];
    const float* b2   = (const float*)d_in[6];
    float* out = (float*)d_out;

    const int nN = in_sizes[0] / IN_F;   // 100000
    const int nE = in_sizes[1];          // 3200000

    int nB = (nN + NPB - 1) >> NPB_SHIFT;  // 782

    // ws layout: feat8 float4[2*nN] | g4 float4[nN] | deg float[nN]
    //          | cursor int[nB] | packed u32[nB*CAPB]
    size_t off_feat8  = 0;
    size_t off_g4     = off_feat8 + (size_t)nN * 2 * sizeof(float4);
    size_t off_deg    = off_g4 + (size_t)nN * sizeof(float4);
    size_t off_cursor = off_deg + (size_t)nN * sizeof(float);
    size_t off_packed = (off_cursor + (size_t)nB * sizeof(int) + 255) & ~(size_t)255;
    size_t need_fast  = off_packed + (size_t)nB * CAPB * sizeof(unsigned);

    bool fast = (ws_size >= need_fast) &&
                (nN <= (int)(SRC_MASK + 1)) &&
                (nB <= MAXB) &&
                (nE / nB <= CAPB - 768);   // mean + ~12 sigma headroom

    if (fast) {
        float4*   feat8  = (float4*)((char*)d_ws + off_feat8);
        float4*   g4     = (float4*)((char*)d_ws + off_g4);
        float*    deg    = (float*)((char*)d_ws + off_deg);
        int*      cursor = (int*)((char*)d_ws + off_cursor);
        unsigned* packed = (unsigned*)((char*)d_ws + off_packed);

        hipMemsetAsync(cursor, 0, (size_t)nB * sizeof(int), stream);
        k_pad<<<(nN + 255) / 256, 256, 0, stream>>>(feat, feat8, nN);
        k_scatter<<<128, 1024, 0, stream>>>(src, dst, nB, cursor, packed, nE);
        k_l1<<<nB, 512, 0, stream>>>(packed, cursor, feat8, W1, b1, W2, g4, deg, nN);
        k_l2<<<nB, 512, 0, stream>>>(packed, cursor, g4, deg, b2, out, nN);
    } else {
        // fallback: atomic-scatter path (needs 10N floats)
        float* deg  = (float*)d_ws;
        float* acc1 = deg + nN;
        float* acc2 = acc1 + (size_t)nN * IN_F;
        const int TB = 256;
        int eblocks = (nE + TB - 1) / TB;
        int nblocks = (nN + TB - 1) / TB;
        hipMemsetAsync(d_ws, 0, (size_t)nN * 10 * sizeof(float), stream);
        scatter1<<<eblocks, TB, 0, stream>>>(src, dst, feat, acc1, deg, nE);
        node_mlp<<<nblocks, TB, 0, stream>>>(acc1, deg, W1, b1, W2, nN);
        scatter2<<<eblocks, TB, 0, stream>>>(src, dst, acc1, acc2, nE);
        finalize<<<nblocks, TB, 0, stream>>>(acc2, deg, b2, out, nN);
    }
}

// Round 5
// 117.214 us; speedup vs baseline: 2.5212x; 2.5212x over previous
//
#include <hip/hip_runtime.h>

// Graph conv x2 (same graph both layers):
//   L1: agg1 = segment_mean(feat[src]->dst); h = relu(agg1@W1+b1)
//   L2: agg2 = segment_mean(h[src]->dst);    out = agg2@W2+b2
// Fused per node: g = relu(mean@W1+b1)@W2 (3 floats) before 2nd aggregation.
//
// Ladder: R0 global-atomic scatter 1594us -> R1 slot-table CSR + register
// aggregation 341us (k_place 290us: 6.4M global ops @ ~22G/s cap; l1+l2 only
// ~45us) -> R2/R3 bucketed LDS-atomic aggregation 251/296us (placement cheap
// but LDS-atomic aggregation ~5x slower than R1's register aggregation).
// R4 = best of both: bucketed placement (cheap) + per-bucket LDS counting
// sort -> sorted per-node CSR, then R1-style node-per-thread REGISTER
// aggregation for both layers. No global atomics outside ~100K reserves.

#define IN_F 6
#define HID_F 32
#define OUT_F 3

#define NPB 128          // nodes per bucket (power of two)
#define NPB_SHIFT 7
#define MAXB 1024        // max buckets supported by scatter LDS histograms
#define CAPB 4864        // per-bucket edge cap (mean ~4093, sd ~64 -> +12 sigma)
#define SRC_BITS 17
#define SRC_MASK ((1u << SRC_BITS) - 1)

// ---------------- bucketize edges by dst range ------------------------------
__global__ void k_scatter(const int* __restrict__ src, const int* __restrict__ dst,
                          int nB, int* __restrict__ cursor_g,
                          unsigned* __restrict__ packed, int nE) {
    __shared__ int hist[MAXB];
    __shared__ int basech[MAXB];
    int per = (nE + gridDim.x - 1) / gridDim.x;
    int e0 = blockIdx.x * per;
    int e1 = min(e0 + per, nE);

    for (int i = threadIdx.x; i < nB; i += blockDim.x) hist[i] = 0;
    __syncthreads();

    for (int e = e0 + threadIdx.x; e < e1; e += blockDim.x)
        atomicAdd(&hist[dst[e] >> NPB_SHIFT], 1);
    __syncthreads();

    for (int b = threadIdx.x; b < nB; b += blockDim.x) {
        int h = hist[b];
        basech[b] = h ? atomicAdd(&cursor_g[b], h) : 0;  // global reserve
        hist[b] = 0;                                     // reuse as place cursor
    }
    __syncthreads();

    for (int e = e0 + threadIdx.x; e < e1; e += blockDim.x) {
        int d = dst[e];
        int b = d >> NPB_SHIFT;
        unsigned dl = (unsigned)(d & (NPB - 1));
        int pos = basech[b] + atomicAdd(&hist[b], 1);
        if (pos < CAPB)
            packed[(size_t)b * CAPB + pos] = (dl << SRC_BITS) | (unsigned)src[e];
    }
}

// ---------------- per-bucket counting sort -> per-node CSR (in place) -------
__global__ void k_sort(unsigned* __restrict__ packed, const int* __restrict__ cursor_g,
                       int* __restrict__ offv, int* __restrict__ cntv, int nN) {
    __shared__ int      hist[NPB];
    __shared__ int      base[NPB];
    __shared__ int      cur[NPB];
    __shared__ unsigned sorted[CAPB];

    int b = blockIdx.x;
    int ecnt = min(cursor_g[b], CAPB);
    unsigned* ep = packed + (size_t)b * CAPB;

    for (int i = threadIdx.x; i < NPB; i += blockDim.x) hist[i] = 0;
    __syncthreads();

    for (int i = threadIdx.x; i < ecnt; i += blockDim.x)
        atomicAdd(&hist[ep[i] >> SRC_BITS], 1);
    __syncthreads();

    if (threadIdx.x == 0) {              // 128-entry serial prefix: ~1K cycles
        int run = 0;
        for (int t = 0; t < NPB; ++t) { base[t] = run; run += hist[t]; }
    }
    __syncthreads();

    int n0 = b << NPB_SHIFT;
    for (int t = threadIdx.x; t < NPB; t += blockDim.x) {
        cur[t] = base[t];
        int n = n0 + t;
        if (n < nN) { offv[n] = b * CAPB + base[t]; cntv[n] = hist[t]; }
    }
    __syncthreads();

    for (int i = threadIdx.x; i < ecnt; i += blockDim.x) {
        unsigned p = ep[i];
        int dl = (int)(p >> SRC_BITS);
        int pos = atomicAdd(&cur[dl], 1);
        sorted[pos] = p & SRC_MASK;
    }
    __syncthreads();

    for (int i = threadIdx.x; i < ecnt; i += blockDim.x) ep[i] = sorted[i];
}

// ---------------- layer 1: node-per-thread register aggregation + MLP -------
__global__ void k_l1(const unsigned* __restrict__ csr, const int* __restrict__ offv,
                     const int* __restrict__ cntv, const float* __restrict__ feat,
                     const float* __restrict__ W1, const float* __restrict__ b1,
                     const float* __restrict__ W2, float4* __restrict__ g4, int nN) {
    __shared__ float sW1[IN_F * HID_F];   // [i][j], stride HID_F
    __shared__ float sb1[HID_F];
    __shared__ float sW2[HID_F * OUT_F];  // [j][k], stride OUT_F
    for (int i = threadIdx.x; i < IN_F * HID_F; i += blockDim.x)  sW1[i] = W1[i];
    for (int i = threadIdx.x; i < HID_F; i += blockDim.x)         sb1[i] = b1[i];
    for (int i = threadIdx.x; i < HID_F * OUT_F; i += blockDim.x) sW2[i] = W2[i];
    __syncthreads();

    int n = blockIdx.x * blockDim.x + threadIdx.x;
    if (n >= nN) return;

    int off = offv[n], c = cntv[n];
    const unsigned* row = csr + off;

    float s0 = 0.f, s1 = 0.f, s2 = 0.f, s3 = 0.f, s4 = 0.f, s5 = 0.f;
#define ACC_FEAT(S)                                                        \
    do {                                                                   \
        const float* f = feat + (size_t)(S) * IN_F;                        \
        float2 f01 = *reinterpret_cast<const float2*>(f + 0);              \
        float2 f23 = *reinterpret_cast<const float2*>(f + 2);              \
        float2 f45 = *reinterpret_cast<const float2*>(f + 4);              \
        s0 += f01.x; s1 += f01.y; s2 += f23.x;                             \
        s3 += f23.y; s4 += f45.x; s5 += f45.y;                             \
    } while (0)

    int i = 0;
    for (; i + 4 <= c; i += 4) {
        unsigned a0 = row[i], a1 = row[i + 1], a2 = row[i + 2], a3 = row[i + 3];
        ACC_FEAT(a0); ACC_FEAT(a1); ACC_FEAT(a2); ACC_FEAT(a3);
    }
    for (; i < c; ++i) ACC_FEAT(row[i]);
#undef ACC_FEAT

    float inv = 1.0f / fmaxf((float)c, 1.0f);
    float a0 = s0 * inv, a1 = s1 * inv, a2 = s2 * inv;
    float a3 = s3 * inv, a4 = s4 * inv, a5 = s5 * inv;

    float g0 = 0.f, g1 = 0.f, g2 = 0.f;
#pragma unroll
    for (int j = 0; j < HID_F; ++j) {
        float t = sb1[j];
        t = fmaf(a0, sW1[0 * HID_F + j], t);
        t = fmaf(a1, sW1[1 * HID_F + j], t);
        t = fmaf(a2, sW1[2 * HID_F + j], t);
        t = fmaf(a3, sW1[3 * HID_F + j], t);
        t = fmaf(a4, sW1[4 * HID_F + j], t);
        t = fmaf(a5, sW1[5 * HID_F + j], t);
        t = fmaxf(t, 0.0f);  // relu
        g0 = fmaf(t, sW2[j * OUT_F + 0], g0);
        g1 = fmaf(t, sW2[j * OUT_F + 1], g1);
        g2 = fmaf(t, sW2[j * OUT_F + 2], g2);
    }
    g4[n] = make_float4(g0, g1, g2, 0.0f);
}

// ---------------- layer 2: node-per-thread register aggregation of g --------
__global__ void k_l2(const unsigned* __restrict__ csr, const int* __restrict__ offv,
                     const int* __restrict__ cntv, const float4* __restrict__ g4,
                     const float* __restrict__ b2, float* __restrict__ out, int nN) {
    int n = blockIdx.x * blockDim.x + threadIdx.x;
    if (n >= nN) return;

    int off = offv[n], c = cntv[n];
    const unsigned* row = csr + off;

    float s0 = 0.f, s1 = 0.f, s2 = 0.f;
    int i = 0;
    for (; i + 4 <= c; i += 4) {
        unsigned a0 = row[i], a1 = row[i + 1], a2 = row[i + 2], a3 = row[i + 3];
        float4 ga = g4[a0], gb = g4[a1], gc = g4[a2], gd = g4[a3];
        s0 += ga.x + gb.x + gc.x + gd.x;
        s1 += ga.y + gb.y + gc.y + gd.y;
        s2 += ga.z + gb.z + gc.z + gd.z;
    }
    for (; i < c; ++i) {
        float4 ga = g4[row[i]];
        s0 += ga.x; s1 += ga.y; s2 += ga.z;
    }

    float inv = 1.0f / fmaxf((float)c, 1.0f);
    out[(size_t)n * OUT_F + 0] = s0 * inv + b2[0];
    out[(size_t)n * OUT_F + 1] = s1 * inv + b2[1];
    out[(size_t)n * OUT_F + 2] = s2 * inv + b2[2];
}

// ===================== fallback path (R0, atomic scatter) ===================
__global__ void scatter1(const int* __restrict__ src, const int* __restrict__ dst,
                         const float* __restrict__ feat,
                         float* __restrict__ acc1, float* __restrict__ deg, int nE) {
    int e = blockIdx.x * blockDim.x + threadIdx.x;
    if (e >= nE) return;
    int s = src[e], d = dst[e];
    const float* f = feat + (size_t)s * IN_F;
    float* a = acc1 + (size_t)d * IN_F;
    float2 f01 = *reinterpret_cast<const float2*>(f + 0);
    float2 f23 = *reinterpret_cast<const float2*>(f + 2);
    float2 f45 = *reinterpret_cast<const float2*>(f + 4);
    atomicAdd(a + 0, f01.x); atomicAdd(a + 1, f01.y); atomicAdd(a + 2, f23.x);
    atomicAdd(a + 3, f23.y); atomicAdd(a + 4, f45.x); atomicAdd(a + 5, f45.y);
    atomicAdd(deg + d, 1.0f);
}

__global__ void node_mlp(float* __restrict__ acc1, const float* __restrict__ deg,
                         const float* __restrict__ W1, const float* __restrict__ b1,
                         const float* __restrict__ W2, int nN) {
    __shared__ float sW1[IN_F * HID_F];
    __shared__ float sb1[HID_F];
    __shared__ float sW2[HID_F * OUT_F];
    for (int i = threadIdx.x; i < IN_F * HID_F; i += blockDim.x)  sW1[i] = W1[i];
    for (int i = threadIdx.x; i < HID_F; i += blockDim.x)         sb1[i] = b1[i];
    for (int i = threadIdx.x; i < HID_F * OUT_F; i += blockDim.x) sW2[i] = W2[i];
    __syncthreads();
    int n = blockIdx.x * blockDim.x + threadIdx.x;
    if (n >= nN) return;
    float inv = 1.0f / fmaxf(deg[n], 1.0f);
    float a[IN_F];
    float* row = acc1 + (size_t)n * IN_F;
#pragma unroll
    for (int i = 0; i < IN_F; ++i) a[i] = row[i] * inv;
    float g0 = 0.f, g1 = 0.f, g2 = 0.f;
#pragma unroll
    for (int j = 0; j < HID_F; ++j) {
        float t = sb1[j];
#pragma unroll
        for (int i = 0; i < IN_F; ++i) t = fmaf(a[i], sW1[i * HID_F + j], t);
        t = fmaxf(t, 0.0f);
        g0 = fmaf(t, sW2[j * OUT_F + 0], g0);
        g1 = fmaf(t, sW2[j * OUT_F + 1], g1);
        g2 = fmaf(t, sW2[j * OUT_F + 2], g2);
    }
    row[0] = g0; row[1] = g1; row[2] = g2;
}

__global__ void scatter2(const int* __restrict__ src, const int* __restrict__ dst,
                         const float* __restrict__ g, float* __restrict__ acc2, int nE) {
    int e = blockIdx.x * blockDim.x + threadIdx.x;
    if (e >= nE) return;
    int s = src[e], d = dst[e];
    const float* gs = g + (size_t)s * IN_F;
    float* a = acc2 + (size_t)d * OUT_F;
    float2 g01 = *reinterpret_cast<const float2*>(gs);
    atomicAdd(a + 0, g01.x); atomicAdd(a + 1, g01.y); atomicAdd(a + 2, gs[2]);
}

__global__ void finalize(const float* __restrict__ acc2, const float* __restrict__ deg,
                         const float* __restrict__ b2, float* __restrict__ out, int nN) {
    int n = blockIdx.x * blockDim.x + threadIdx.x;
    if (n >= nN) return;
    float inv = 1.0f / fmaxf(deg[n], 1.0f);
    out[(size_t)n * OUT_F + 0] = acc2[(size_t)n * OUT_F + 0] * inv + b2[0];
    out[(size_t)n * OUT_F + 1] = acc2[(size_t)n * OUT_F + 1] * inv + b2[1];
    out[(size_t)n * OUT_F + 2] = acc2[(size_t)n * OUT_F + 2] * inv + b2[2];
}

// ============================================================================
extern "C" void kernel_launch(void* const* d_in, const int* in_sizes, int n_in,
                              void* d_out, int out_size, void* d_ws, size_t ws_size,
                              hipStream_t stream) {
    const float* feat = (const float*)d_in[0];
    const int*   src  = (const int*)d_in[1];
    const int*   dst  = (const int*)d_in[2];
    const float* W1   = (const float*)d_in[3];
    const float* b1   = (const float*)d_in[4];
    const float* W2   = (const float*)d_in[5];
    const float* b2   = (const float*)d_in[6];
    float* out = (float*)d_out;

    const int nN = in_sizes[0] / IN_F;   // 100000
    const int nE = in_sizes[1];          // 3200000

    int nB = (nN + NPB - 1) >> NPB_SHIFT;  // 782

    // ws layout: g4 float4[nN] | offv int[nN] | cntv int[nN]
    //          | cursor int[nB] | packed u32[nB*CAPB] (sorted in place -> csr)
    size_t off_g4     = 0;
    size_t off_offv   = off_g4 + (size_t)nN * sizeof(float4);
    size_t off_cntv   = off_offv + (size_t)nN * sizeof(int);
    size_t off_cursor = off_cntv + (size_t)nN * sizeof(int);
    size_t off_packed = (off_cursor + (size_t)nB * sizeof(int) + 255) & ~(size_t)255;
    size_t need_fast  = off_packed + (size_t)nB * CAPB * sizeof(unsigned);

    bool fast = (ws_size >= need_fast) &&
                (nN <= (int)(SRC_MASK + 1)) &&
                (nB <= MAXB) &&
                (nE / nB <= CAPB - 768);   // mean + ~12 sigma headroom

    if (fast) {
        float4*   g4     = (float4*)((char*)d_ws + off_g4);
        int*      offv   = (int*)((char*)d_ws + off_offv);
        int*      cntv   = (int*)((char*)d_ws + off_cntv);
        int*      cursor = (int*)((char*)d_ws + off_cursor);
        unsigned* packed = (unsigned*)((char*)d_ws + off_packed);

        hipMemsetAsync(cursor, 0, (size_t)nB * sizeof(int), stream);
        k_scatter<<<128, 1024, 0, stream>>>(src, dst, nB, cursor, packed, nE);
        k_sort<<<nB, 256, 0, stream>>>(packed, cursor, offv, cntv, nN);
        k_l1<<<(nN + 255) / 256, 256, 0, stream>>>(packed, offv, cntv, feat,
                                                   W1, b1, W2, g4, nN);
        k_l2<<<(nN + 255) / 256, 256, 0, stream>>>(packed, offv, cntv, g4, b2, out, nN);
    } else {
        // fallback: atomic-scatter path (needs 10N floats)
        float* deg  = (float*)d_ws;
        float* acc1 = deg + nN;
        float* acc2 = acc1 + (size_t)nN * IN_F;
        const int TB = 256;
        int eblocks = (nE + TB - 1) / TB;
        int nblocks = (nN + TB - 1) / TB;
        hipMemsetAsync(d_ws, 0, (size_t)nN * 10 * sizeof(float), stream);
        scatter1<<<eblocks, TB, 0, stream>>>(src, dst, feat, acc1, deg, nE);
        node_mlp<<<nblocks, TB, 0, stream>>>(acc1, deg, W1, b1, W2, nN);
        scatter2<<<eblocks, TB, 0, stream>>>(src, dst, acc1, acc2, nE);
        finalize<<<nblocks, TB, 0, stream>>>(acc2, deg, b2, out, nN);
    }
}

// Round 7
// 92.947 us; speedup vs baseline: 3.1795x; 1.2611x over previous
//
#include <hip/hip_runtime.h>

// Graph conv x2 (same graph both layers):
//   L1: agg1 = segment_mean(feat[src]->dst); h = relu(agg1@W1+b1)
//   L2: agg2 = segment_mean(h[src]->dst);    out = agg2@W2+b2
// Fused per node: g = relu(mean@W1+b1)@W2 (3 floats) before 2nd aggregation.
//
// Ladder: R0 1594us (global atomics ~22G ops/s cap) -> R1 341us -> R2/R3
// 251/296us (LDS-atomic agg 5x slower than register agg) -> R4 117us
// (bucketed placement + counting sort -> sorted CSR + register aggregation)
// -> R5 crashed: divergent __syncthreads in k_scatter (nB=391 not
// wave-aligned; boundary wave ran BOTH barrier paths). R6 = R5 with
// barriers hoisted out of conditionals (values carried in registers).

#define IN_F 6
#define HID_F 32
#define OUT_F 3

#define NPB 256          // nodes per bucket (power of two)
#define NPB_SHIFT 8
#define NBMAX 512        // max buckets (LDS arrays in k_scatter)
#define CAPB 9728        // per-bucket edge cap (mean ~8184, sd ~90 -> +17 sigma)
#define CHUNK 8192       // edges per scatter block (LDS-sorted)
#define SRC_BITS 17
#define SRC_MASK ((1u << SRC_BITS) - 1)

// ---------------- bucketize edges: per-chunk LDS sort, coalesced write ------
__global__ __launch_bounds__(1024)
void k_scatter(const int* __restrict__ src, const int* __restrict__ dst,
               int nB, int* __restrict__ cursor_g,
               unsigned* __restrict__ packed, int nE) {
    __shared__ int      hist[NBMAX];
    __shared__ int      base_l[NBMAX];   // exclusive prefix within chunk
    __shared__ int      base_g[NBMAX];   // reserved global base within bucket
    __shared__ int      cur[NBMAX];
    __shared__ unsigned sorted_l[CHUNK];
    __shared__ unsigned short bkt_l[CHUNK];

    const int tid = threadIdx.x;
    int e0 = blockIdx.x * CHUNK;
    int e1 = min(e0 + CHUNK, nE);
    int cnt = e1 - e0;

    for (int b = tid; b < nB; b += blockDim.x) hist[b] = 0;
    __syncthreads();

    // pass 1: histogram by bucket
    for (int e = e0 + tid; e < e1; e += blockDim.x)
        atomicAdd(&hist[dst[e] >> NPB_SHIFT], 1);
    __syncthreads();

    // inclusive Hillis-Steele scan of hist into base_l (barriers unconditional)
    if (tid < nB) base_l[tid] = hist[tid];
    __syncthreads();
    for (int off = 1; off < nB; off <<= 1) {
        int v = 0;
        if (tid < nB) {
            v = base_l[tid];
            if (tid >= off) v += base_l[tid - off];
        }
        __syncthreads();
        if (tid < nB) base_l[tid] = v;
        __syncthreads();
    }

    // exclusive prefix + global reserve — NO barrier inside conditionals
    int h_r = 0, ex_r = 0;
    if (tid < nB) {
        h_r  = hist[tid];
        ex_r = base_l[tid] - h_r;              // read inclusive scan
        base_g[tid] = h_r ? atomicAdd(&cursor_g[tid], h_r) : 0;
        cur[tid] = ex_r;
    }
    __syncthreads();                            // everyone done reading base_l
    if (tid < nB) base_l[tid] = ex_r;           // now safe to overwrite
    __syncthreads();

    // pass 2: place into LDS, sorted by bucket
    for (int e = e0 + tid; e < e1; e += blockDim.x) {
        int d = dst[e];
        int b = d >> NPB_SHIFT;
        unsigned rec = ((unsigned)(d & (NPB - 1)) << SRC_BITS) | (unsigned)src[e];
        int p = atomicAdd(&cur[b], 1);
        sorted_l[p] = rec;
        bkt_l[p] = (unsigned short)b;
    }
    __syncthreads();

    // pass 3: position-ordered copy-out (coalesced within bucket runs)
    for (int i = tid; i < cnt; i += blockDim.x) {
        int b = bkt_l[i];
        int rel = base_g[b] + (i - base_l[b]);
        if (rel < CAPB) packed[(size_t)b * CAPB + rel] = sorted_l[i];
    }
}

// ---------------- per-bucket counting sort -> per-node CSR (in place) -------
__global__ __launch_bounds__(1024)
void k_sort(unsigned* __restrict__ packed, const int* __restrict__ cursor_g,
            int* __restrict__ offv, int* __restrict__ cntv, int nN) {
    __shared__ int      hist[NPB];
    __shared__ int      base[NPB];
    __shared__ int      cur[NPB];
    __shared__ unsigned sorted[CAPB];

    const int tid = threadIdx.x;
    int b = blockIdx.x;
    int ecnt = min(cursor_g[b], CAPB);
    unsigned* ep = packed + (size_t)b * CAPB;

    if (tid < NPB) hist[tid] = 0;
    __syncthreads();

    for (int i = tid; i < ecnt; i += blockDim.x)
        atomicAdd(&hist[ep[i] >> SRC_BITS], 1);
    __syncthreads();

    // inclusive H-S scan over NPB entries (barriers unconditional)
    if (tid < NPB) base[tid] = hist[tid];
    __syncthreads();
    for (int off = 1; off < NPB; off <<= 1) {
        int v = 0;
        if (tid < NPB) {
            v = base[tid];
            if (tid >= off) v += base[tid - off];
        }
        __syncthreads();
        if (tid < NPB) base[tid] = v;
        __syncthreads();
    }

    int n0 = b << NPB_SHIFT;
    int h_r = 0, ex_r = 0;
    if (tid < NPB) {
        h_r  = hist[tid];
        ex_r = base[tid] - h_r;
        cur[tid] = ex_r;
        int n = n0 + tid;
        if (n < nN) { offv[n] = b * CAPB + ex_r; cntv[n] = h_r; }
    }
    __syncthreads();
    if (tid < NPB) base[tid] = ex_r;
    __syncthreads();

    for (int i = tid; i < ecnt; i += blockDim.x) {
        unsigned p = ep[i];
        int dl = (int)(p >> SRC_BITS);
        int pos = atomicAdd(&cur[dl], 1);
        sorted[pos] = p & SRC_MASK;
    }
    __syncthreads();

    for (int i = tid; i < ecnt; i += blockDim.x) ep[i] = sorted[i];
}

// ---------------- layer 1: node-per-thread register aggregation + MLP -------
__global__ void k_l1(const unsigned* __restrict__ csr, const int* __restrict__ offv,
                     const int* __restrict__ cntv, const float* __restrict__ feat,
                     const float* __restrict__ W1, const float* __restrict__ b1,
                     const float* __restrict__ W2, float4* __restrict__ g4, int nN) {
    __shared__ float sW1[IN_F * HID_F];   // [i][j], stride HID_F
    __shared__ float sb1[HID_F];
    __shared__ float sW2[HID_F * OUT_F];  // [j][k], stride OUT_F
    for (int i = threadIdx.x; i < IN_F * HID_F; i += blockDim.x)  sW1[i] = W1[i];
    for (int i = threadIdx.x; i < HID_F; i += blockDim.x)         sb1[i] = b1[i];
    for (int i = threadIdx.x; i < HID_F * OUT_F; i += blockDim.x) sW2[i] = W2[i];
    __syncthreads();

    int n = blockIdx.x * blockDim.x + threadIdx.x;
    if (n >= nN) return;

    int off = offv[n], c = cntv[n];
    const unsigned* row = csr + off;

    float s0 = 0.f, s1 = 0.f, s2 = 0.f, s3 = 0.f, s4 = 0.f, s5 = 0.f;
#define ACC_FEAT(S)                                                        \
    do {                                                                   \
        const float* f = feat + (size_t)(S) * IN_F;                        \
        float2 f01 = *reinterpret_cast<const float2*>(f + 0);              \
        float2 f23 = *reinterpret_cast<const float2*>(f + 2);              \
        float2 f45 = *reinterpret_cast<const float2*>(f + 4);              \
        s0 += f01.x; s1 += f01.y; s2 += f23.x;                             \
        s3 += f23.y; s4 += f45.x; s5 += f45.y;                             \
    } while (0)

    int i = 0;
    for (; i + 4 <= c; i += 4) {
        unsigned a0 = row[i], a1 = row[i + 1], a2 = row[i + 2], a3 = row[i + 3];
        ACC_FEAT(a0); ACC_FEAT(a1); ACC_FEAT(a2); ACC_FEAT(a3);
    }
    for (; i < c; ++i) ACC_FEAT(row[i]);
#undef ACC_FEAT

    float inv = 1.0f / fmaxf((float)c, 1.0f);
    float a0 = s0 * inv, a1 = s1 * inv, a2 = s2 * inv;
    float a3 = s3 * inv, a4 = s4 * inv, a5 = s5 * inv;

    float g0 = 0.f, g1 = 0.f, g2 = 0.f;
#pragma unroll
    for (int j = 0; j < HID_F; ++j) {
        float t = sb1[j];
        t = fmaf(a0, sW1[0 * HID_F + j], t);
        t = fmaf(a1, sW1[1 * HID_F + j], t);
        t = fmaf(a2, sW1[2 * HID_F + j], t);
        t = fmaf(a3, sW1[3 * HID_F + j], t);
        t = fmaf(a4, sW1[4 * HID_F + j], t);
        t = fmaf(a5, sW1[5 * HID_F + j], t);
        t = fmaxf(t, 0.0f);  // relu
        g0 = fmaf(t, sW2[j * OUT_F + 0], g0);
        g1 = fmaf(t, sW2[j * OUT_F + 1], g1);
        g2 = fmaf(t, sW2[j * OUT_F + 2], g2);
    }
    g4[n] = make_float4(g0, g1, g2, 0.0f);
}

// ---------------- layer 2: node-per-thread register aggregation of g --------
__global__ void k_l2(const unsigned* __restrict__ csr, const int* __restrict__ offv,
                     const int* __restrict__ cntv, const float4* __restrict__ g4,
                     const float* __restrict__ b2, float* __restrict__ out, int nN) {
    int n = blockIdx.x * blockDim.x + threadIdx.x;
    if (n >= nN) return;

    int off = offv[n], c = cntv[n];
    const unsigned* row = csr + off;

    float s0 = 0.f, s1 = 0.f, s2 = 0.f;
    int i = 0;
    for (; i + 4 <= c; i += 4) {
        unsigned a0 = row[i], a1 = row[i + 1], a2 = row[i + 2], a3 = row[i + 3];
        float4 ga = g4[a0], gb = g4[a1], gc = g4[a2], gd = g4[a3];
        s0 += ga.x + gb.x + gc.x + gd.x;
        s1 += ga.y + gb.y + gc.y + gd.y;
        s2 += ga.z + gb.z + gc.z + gd.z;
    }
    for (; i < c; ++i) {
        float4 ga = g4[row[i]];
        s0 += ga.x; s1 += ga.y; s2 += ga.z;
    }

    float inv = 1.0f / fmaxf((float)c, 1.0f);
    out[(size_t)n * OUT_F + 0] = s0 * inv + b2[0];
    out[(size_t)n * OUT_F + 1] = s1 * inv + b2[1];
    out[(size_t)n * OUT_F + 2] = s2 * inv + b2[2];
}

// ===================== fallback path (R0, atomic scatter) ===================
__global__ void scatter1(const int* __restrict__ src, const int* __restrict__ dst,
                         const float* __restrict__ feat,
                         float* __restrict__ acc1, float* __restrict__ deg, int nE) {
    int e = blockIdx.x * blockDim.x + threadIdx.x;
    if (e >= nE) return;
    int s = src[e], d = dst[e];
    const float* f = feat + (size_t)s * IN_F;
    float* a = acc1 + (size_t)d * IN_F;
    float2 f01 = *reinterpret_cast<const float2*>(f + 0);
    float2 f23 = *reinterpret_cast<const float2*>(f + 2);
    float2 f45 = *reinterpret_cast<const float2*>(f + 4);
    atomicAdd(a + 0, f01.x); atomicAdd(a + 1, f01.y); atomicAdd(a + 2, f23.x);
    atomicAdd(a + 3, f23.y); atomicAdd(a + 4, f45.x); atomicAdd(a + 5, f45.y);
    atomicAdd(deg + d, 1.0f);
}

__global__ void node_mlp(float* __restrict__ acc1, const float* __restrict__ deg,
                         const float* __restrict__ W1, const float* __restrict__ b1,
                         const float* __restrict__ W2, int nN) {
    __shared__ float sW1[IN_F * HID_F];
    __shared__ float sb1[HID_F];
    __shared__ float sW2[HID_F * OUT_F];
    for (int i = threadIdx.x; i < IN_F * HID_F; i += blockDim.x)  sW1[i] = W1[i];
    for (int i = threadIdx.x; i < HID_F; i += blockDim.x)         sb1[i] = b1[i];
    for (int i = threadIdx.x; i < HID_F * OUT_F; i += blockDim.x) sW2[i] = W2[i];
    __syncthreads();
    int n = blockIdx.x * blockDim.x + threadIdx.x;
    if (n >= nN) return;
    float inv = 1.0f / fmaxf(deg[n], 1.0f);
    float a[IN_F];
    float* row = acc1 + (size_t)n * IN_F;
#pragma unroll
    for (int i = 0; i < IN_F; ++i) a[i] = row[i] * inv;
    float g0 = 0.f, g1 = 0.f, g2 = 0.f;
#pragma unroll
    for (int j = 0; j < HID_F; ++j) {
        float t = sb1[j];
#pragma unroll
        for (int i = 0; i < IN_F; ++i) t = fmaf(a[i], sW1[i * HID_F + j], t);
        t = fmaxf(t, 0.0f);
        g0 = fmaf(t, sW2[j * OUT_F + 0], g0);
        g1 = fmaf(t, sW2[j * OUT_F + 1], g1);
        g2 = fmaf(t, sW2[j * OUT_F + 2], g2);
    }
    row[0] = g0; row[1] = g1; row[2] = g2;
}

__global__ void scatter2(const int* __restrict__ src, const int* __restrict__ dst,
                         const float* __restrict__ g, float* __restrict__ acc2, int nE) {
    int e = blockIdx.x * blockDim.x + threadIdx.x;
    if (e >= nE) return;
    int s = src[e], d = dst[e];
    const float* gs = g + (size_t)s * IN_F;
    float* a = acc2 + (size_t)d * OUT_F;
    float2 g01 = *reinterpret_cast<const float2*>(gs);
    atomicAdd(a + 0, g01.x); atomicAdd(a + 1, g01.y); atomicAdd(a + 2, gs[2]);
}

__global__ void finalize(const float* __restrict__ acc2, const float* __restrict__ deg,
                         const float* __restrict__ b2, float* __restrict__ out, int nN) {
    int n = blockIdx.x * blockDim.x + threadIdx.x;
    if (n >= nN) return;
    float inv = 1.0f / fmaxf(deg[n], 1.0f);
    out[(size_t)n * OUT_F + 0] = acc2[(size_t)n * OUT_F + 0] * inv + b2[0];
    out[(size_t)n * OUT_F + 1] = acc2[(size_t)n * OUT_F + 1] * inv + b2[1];
    out[(size_t)n * OUT_F + 2] = acc2[(size_t)n * OUT_F + 2] * inv + b2[2];
}

// ============================================================================
extern "C" void kernel_launch(void* const* d_in, const int* in_sizes, int n_in,
                              void* d_out, int out_size, void* d_ws, size_t ws_size,
                              hipStream_t stream) {
    const float* feat = (const float*)d_in[0];
    const int*   src  = (const int*)d_in[1];
    const int*   dst  = (const int*)d_in[2];
    const float* W1   = (const float*)d_in[3];
    const float* b1   = (const float*)d_in[4];
    const float* W2   = (const float*)d_in[5];
    const float* b2   = (const float*)d_in[6];
    float* out = (float*)d_out;

    const int nN = in_sizes[0] / IN_F;   // 100000
    const int nE = in_sizes[1];          // 3200000

    int nB = (nN + NPB - 1) >> NPB_SHIFT;  // 391
    int nC = (nE + CHUNK - 1) / CHUNK;     // 391

    // ws layout: g4 float4[nN] | offv int[nN] | cntv int[nN]
    //          | cursor int[nB] | packed u32[nB*CAPB] (sorted in place -> csr)
    size_t off_g4     = 0;
    size_t off_offv   = off_g4 + (size_t)nN * sizeof(float4);
    size_t off_cntv   = off_offv + (size_t)nN * sizeof(int);
    size_t off_cursor = off_cntv + (size_t)nN * sizeof(int);
    size_t off_packed = (off_cursor + (size_t)nB * sizeof(int) + 255) & ~(size_t)255;
    size_t need_fast  = off_packed + (size_t)nB * CAPB * sizeof(unsigned);

    bool fast = (ws_size >= need_fast) &&
                (nN <= (int)(SRC_MASK + 1)) &&
                (nB <= NBMAX) &&
                (nE / nB <= CAPB - 1500);   // mean + ~17 sigma headroom

    if (fast) {
        float4*   g4     = (float4*)((char*)d_ws + off_g4);
        int*      offv   = (int*)((char*)d_ws + off_offv);
        int*      cntv   = (int*)((char*)d_ws + off_cntv);
        int*      cursor = (int*)((char*)d_ws + off_cursor);
        unsigned* packed = (unsigned*)((char*)d_ws + off_packed);

        hipMemsetAsync(cursor, 0, (size_t)nB * sizeof(int), stream);
        k_scatter<<<nC, 1024, 0, stream>>>(src, dst, nB, cursor, packed, nE);
        k_sort<<<nB, 1024, 0, stream>>>(packed, cursor, offv, cntv, nN);
        k_l1<<<(nN + 255) / 256, 256, 0, stream>>>(packed, offv, cntv, feat,
                                                   W1, b1, W2, g4, nN);
        k_l2<<<(nN + 255) / 256, 256, 0, stream>>>(packed, offv, cntv, g4, b2, out, nN);
    } else {
        // fallback: atomic-scatter path (needs 10N floats)
        float* deg  = (float*)d_ws;
        float* acc1 = deg + nN;
        float* acc2 = acc1 + (size_t)nN * IN_F;
        const int TB = 256;
        int eblocks = (nE + TB - 1) / TB;
        int nblocks = (nN + TB - 1) / TB;
        hipMemsetAsync(d_ws, 0, (size_t)nN * 10 * sizeof(float), stream);
        scatter1<<<eblocks, TB, 0, stream>>>(src, dst, feat, acc1, deg, nE);
        node_mlp<<<nblocks, TB, 0, stream>>>(acc1, deg, W1, b1, W2, nN);
        scatter2<<<eblocks, TB, 0, stream>>>(src, dst, acc1, acc2, nE);
        finalize<<<nblocks, TB, 0, stream>>>(acc2, deg, b2, out, nN);
    }
}

// Round 8
// 78.626 us; speedup vs baseline: 3.7586x; 1.1821x over previous
//
#include <hip/hip_runtime.h>

// Graph conv x2 (same graph both layers):
//   L1: agg1 = segment_mean(feat[src]->dst); h = relu(agg1@W1+b1)
//   L2: agg2 = segment_mean(h[src]->dst);    out = agg2@W2+b2
// Fused per node: g = relu(mean@W1+b1)@W2 (3 floats) before 2nd aggregation.
//
// Ladder: R0 1594us (global atomics ~22G ops/s) -> R1 341 -> R2/R3 251/296
// (LDS-atomic agg 5x slower than register agg) -> R4 117 (bucket+sort CSR +
// register agg) -> R6 92.9 (chunk-LDS-sorted coalesced scatter; barriers
// wave-safe). R6 profile: 1.5KB hipMemsetAsync -> fillBufferAligned node
// costs ~42us (!) and sort->l1 round-trips 2x12.8MB through HBM.
// R7: k_zero kernel replaces memset; k_sl1 fuses sort+l1 (aggregate from
// LDS, 4 lanes/node, shfl reduce; sorted run still written out for l2).

#define IN_F 6
#define HID_F 32
#define OUT_F 3

#define NPB 256          // nodes per bucket (power of two)
#define NPB_SHIFT 8
#define NBMAX 512        // max buckets (LDS arrays in k_scatter)
#define CAPB 9728        // per-bucket edge cap (mean ~8184, sd ~90 -> +17 sigma)
#define CHUNK 8192       // edges per scatter block (LDS-sorted)
#define SRC_BITS 17
#define SRC_MASK ((1u << SRC_BITS) - 1)

// ---------------- zero the bucket cursors (replaces 42us memset node) -------
__global__ void k_zero(int* __restrict__ cursor, int nB) {
    for (int i = threadIdx.x; i < nB; i += blockDim.x) cursor[i] = 0;
}

// ---------------- bucketize edges: per-chunk LDS sort, coalesced write ------
__global__ __launch_bounds__(1024)
void k_scatter(const int* __restrict__ src, const int* __restrict__ dst,
               int nB, int* __restrict__ cursor_g,
               unsigned* __restrict__ packed, int nE) {
    __shared__ int      hist[NBMAX];
    __shared__ int      base_l[NBMAX];   // exclusive prefix within chunk
    __shared__ int      base_g[NBMAX];   // reserved global base within bucket
    __shared__ int      cur[NBMAX];
    __shared__ unsigned sorted_l[CHUNK];
    __shared__ unsigned short bkt_l[CHUNK];

    const int tid = threadIdx.x;
    int e0 = blockIdx.x * CHUNK;
    int e1 = min(e0 + CHUNK, nE);
    int cnt = e1 - e0;

    for (int b = tid; b < nB; b += blockDim.x) hist[b] = 0;
    __syncthreads();

    for (int e = e0 + tid; e < e1; e += blockDim.x)
        atomicAdd(&hist[dst[e] >> NPB_SHIFT], 1);
    __syncthreads();

    // inclusive Hillis-Steele scan of hist into base_l (barriers unconditional)
    if (tid < nB) base_l[tid] = hist[tid];
    __syncthreads();
    for (int off = 1; off < nB; off <<= 1) {
        int v = 0;
        if (tid < nB) {
            v = base_l[tid];
            if (tid >= off) v += base_l[tid - off];
        }
        __syncthreads();
        if (tid < nB) base_l[tid] = v;
        __syncthreads();
    }

    // exclusive prefix + global reserve — no barrier inside conditionals
    int h_r = 0, ex_r = 0;
    if (tid < nB) {
        h_r  = hist[tid];
        ex_r = base_l[tid] - h_r;
        base_g[tid] = h_r ? atomicAdd(&cursor_g[tid], h_r) : 0;
        cur[tid] = ex_r;
    }
    __syncthreads();
    if (tid < nB) base_l[tid] = ex_r;
    __syncthreads();

    // place into LDS, sorted by bucket
    for (int e = e0 + tid; e < e1; e += blockDim.x) {
        int d = dst[e];
        int b = d >> NPB_SHIFT;
        unsigned rec = ((unsigned)(d & (NPB - 1)) << SRC_BITS) | (unsigned)src[e];
        int p = atomicAdd(&cur[b], 1);
        sorted_l[p] = rec;
        bkt_l[p] = (unsigned short)b;
    }
    __syncthreads();

    // position-ordered copy-out (coalesced within bucket runs)
    for (int i = tid; i < cnt; i += blockDim.x) {
        int b = bkt_l[i];
        int rel = base_g[b] + (i - base_l[b]);
        if (rel < CAPB) packed[(size_t)b * CAPB + rel] = sorted_l[i];
    }
}

// ------- fused: per-bucket counting sort (LDS) + layer-1 aggregation --------
// Sorted run written back to `packed` (layer 2 re-reads it); aggregation is
// done from LDS with 4 lanes per node + shfl reduction; the 4 lanes then
// split the 32-wide MLP and shfl-reduce g0..g2.
__global__ __launch_bounds__(1024)
void k_sl1(unsigned* __restrict__ packed, const int* __restrict__ cursor_g,
           const float* __restrict__ feat,
           const float* __restrict__ W1, const float* __restrict__ b1,
           const float* __restrict__ W2,
           float4* __restrict__ g4, int* __restrict__ offv, int* __restrict__ cntv,
           int nN) {
    __shared__ int      hist[NPB];
    __shared__ int      base[NPB];     // ends as exclusive prefix (run start)
    __shared__ int      cur[NPB];
    __shared__ unsigned sorted[CAPB];
    __shared__ float    sW1[IN_F * HID_F];   // [i][j], stride HID_F
    __shared__ float    sb1[HID_F];
    __shared__ float    sW2[HID_F * OUT_F];  // [j][k], stride OUT_F

    const int tid = threadIdx.x;
    int b = blockIdx.x;
    int ecnt = min(cursor_g[b], CAPB);
    unsigned* ep = packed + (size_t)b * CAPB;

    for (int i = tid; i < IN_F * HID_F; i += blockDim.x)  sW1[i] = W1[i];
    for (int i = tid; i < HID_F; i += blockDim.x)         sb1[i] = b1[i];
    for (int i = tid; i < HID_F * OUT_F; i += blockDim.x) sW2[i] = W2[i];
    if (tid < NPB) hist[tid] = 0;
    __syncthreads();

    for (int i = tid; i < ecnt; i += blockDim.x)
        atomicAdd(&hist[ep[i] >> SRC_BITS], 1);
    __syncthreads();

    // inclusive H-S scan (barriers unconditional)
    if (tid < NPB) base[tid] = hist[tid];
    __syncthreads();
    for (int off = 1; off < NPB; off <<= 1) {
        int v = 0;
        if (tid < NPB) {
            v = base[tid];
            if (tid >= off) v += base[tid - off];
        }
        __syncthreads();
        if (tid < NPB) base[tid] = v;
        __syncthreads();
    }

    int n0 = b << NPB_SHIFT;
    int h_r = 0, ex_r = 0;
    if (tid < NPB) {
        h_r  = hist[tid];
        ex_r = base[tid] - h_r;
        cur[tid] = ex_r;
        int n = n0 + tid;
        if (n < nN) { offv[n] = b * CAPB + ex_r; cntv[n] = h_r; }
    }
    __syncthreads();
    if (tid < NPB) base[tid] = ex_r;
    __syncthreads();

    // counting-sort into LDS
    for (int i = tid; i < ecnt; i += blockDim.x) {
        unsigned p = ep[i];
        int dl = (int)(p >> SRC_BITS);
        int pos = atomicAdd(&cur[dl], 1);
        sorted[pos] = p & SRC_MASK;
    }
    __syncthreads();

    // write sorted run back for layer 2 (coalesced)
    for (int i = tid; i < ecnt; i += blockDim.x) ep[i] = sorted[i];

    // ---- layer-1 aggregation from LDS: 4 lanes per node ----
    int node = tid >> 2;          // 0..255
    int sub  = tid & 3;
    int n    = n0 + node;
    bool live = (n < nN);

    float s0 = 0.f, s1 = 0.f, s2 = 0.f, s3 = 0.f, s4 = 0.f, s5 = 0.f;
    int st = 0, c = 0;
    if (live) { st = base[node]; c = hist[node]; }

    for (int i = st + sub; i < st + c; i += 4) {
        unsigned s = sorted[i];
        const float* f = feat + (size_t)s * IN_F;
        float2 f01 = *reinterpret_cast<const float2*>(f + 0);
        float2 f23 = *reinterpret_cast<const float2*>(f + 2);
        float2 f45 = *reinterpret_cast<const float2*>(f + 4);
        s0 += f01.x; s1 += f01.y; s2 += f23.x;
        s3 += f23.y; s4 += f45.x; s5 += f45.y;
    }
    // reduce the 4 sub-lanes (adjacent lanes in one wave)
    s0 += __shfl_xor(s0, 1); s0 += __shfl_xor(s0, 2);
    s1 += __shfl_xor(s1, 1); s1 += __shfl_xor(s1, 2);
    s2 += __shfl_xor(s2, 1); s2 += __shfl_xor(s2, 2);
    s3 += __shfl_xor(s3, 1); s3 += __shfl_xor(s3, 2);
    s4 += __shfl_xor(s4, 1); s4 += __shfl_xor(s4, 2);
    s5 += __shfl_xor(s5, 1); s5 += __shfl_xor(s5, 2);

    float inv = 1.0f / fmaxf((float)c, 1.0f);
    float a0 = s0 * inv, a1 = s1 * inv, a2 = s2 * inv;
    float a3 = s3 * inv, a4 = s4 * inv, a5 = s5 * inv;

    // each sub-lane computes 8 of the 32 hidden units
    float g0 = 0.f, g1 = 0.f, g2 = 0.f;
    int j0 = sub * (HID_F / 4);
#pragma unroll
    for (int jj = 0; jj < HID_F / 4; ++jj) {
        int j = j0 + jj;
        float t = sb1[j];
        t = fmaf(a0, sW1[0 * HID_F + j], t);
        t = fmaf(a1, sW1[1 * HID_F + j], t);
        t = fmaf(a2, sW1[2 * HID_F + j], t);
        t = fmaf(a3, sW1[3 * HID_F + j], t);
        t = fmaf(a4, sW1[4 * HID_F + j], t);
        t = fmaf(a5, sW1[5 * HID_F + j], t);
        t = fmaxf(t, 0.0f);  // relu
        g0 = fmaf(t, sW2[j * OUT_F + 0], g0);
        g1 = fmaf(t, sW2[j * OUT_F + 1], g1);
        g2 = fmaf(t, sW2[j * OUT_F + 2], g2);
    }
    g0 += __shfl_xor(g0, 1); g0 += __shfl_xor(g0, 2);
    g1 += __shfl_xor(g1, 1); g1 += __shfl_xor(g1, 2);
    g2 += __shfl_xor(g2, 1); g2 += __shfl_xor(g2, 2);

    if (live && sub == 0) g4[n] = make_float4(g0, g1, g2, 0.0f);
}

// ---------------- layer 2: node-per-thread register aggregation of g --------
__global__ void k_l2(const unsigned* __restrict__ csr, const int* __restrict__ offv,
                     const int* __restrict__ cntv, const float4* __restrict__ g4,
                     const float* __restrict__ b2, float* __restrict__ out, int nN) {
    int n = blockIdx.x * blockDim.x + threadIdx.x;
    if (n >= nN) return;

    int off = offv[n], c = cntv[n];
    const unsigned* row = csr + off;

    float s0 = 0.f, s1 = 0.f, s2 = 0.f;
    int i = 0;
    for (; i + 4 <= c; i += 4) {
        unsigned a0 = row[i], a1 = row[i + 1], a2 = row[i + 2], a3 = row[i + 3];
        float4 ga = g4[a0], gb = g4[a1], gc = g4[a2], gd = g4[a3];
        s0 += ga.x + gb.x + gc.x + gd.x;
        s1 += ga.y + gb.y + gc.y + gd.y;
        s2 += ga.z + gb.z + gc.z + gd.z;
    }
    for (; i < c; ++i) {
        float4 ga = g4[row[i]];
        s0 += ga.x; s1 += ga.y; s2 += ga.z;
    }

    float inv = 1.0f / fmaxf((float)c, 1.0f);
    out[(size_t)n * OUT_F + 0] = s0 * inv + b2[0];
    out[(size_t)n * OUT_F + 1] = s1 * inv + b2[1];
    out[(size_t)n * OUT_F + 2] = s2 * inv + b2[2];
}

// ===================== fallback path (R0, atomic scatter) ===================
__global__ void scatter1(const int* __restrict__ src, const int* __restrict__ dst,
                         const float* __restrict__ feat,
                         float* __restrict__ acc1, float* __restrict__ deg, int nE) {
    int e = blockIdx.x * blockDim.x + threadIdx.x;
    if (e >= nE) return;
    int s = src[e], d = dst[e];
    const float* f = feat + (size_t)s * IN_F;
    float* a = acc1 + (size_t)d * IN_F;
    float2 f01 = *reinterpret_cast<const float2*>(f + 0);
    float2 f23 = *reinterpret_cast<const float2*>(f + 2);
    float2 f45 = *reinterpret_cast<const float2*>(f + 4);
    atomicAdd(a + 0, f01.x); atomicAdd(a + 1, f01.y); atomicAdd(a + 2, f23.x);
    atomicAdd(a + 3, f23.y); atomicAdd(a + 4, f45.x); atomicAdd(a + 5, f45.y);
    atomicAdd(deg + d, 1.0f);
}

__global__ void node_mlp(float* __restrict__ acc1, const float* __restrict__ deg,
                         const float* __restrict__ W1, const float* __restrict__ b1,
                         const float* __restrict__ W2, int nN) {
    __shared__ float sW1[IN_F * HID_F];
    __shared__ float sb1[HID_F];
    __shared__ float sW2[HID_F * OUT_F];
    for (int i = threadIdx.x; i < IN_F * HID_F; i += blockDim.x)  sW1[i] = W1[i];
    for (int i = threadIdx.x; i < HID_F; i += blockDim.x)         sb1[i] = b1[i];
    for (int i = threadIdx.x; i < HID_F * OUT_F; i += blockDim.x) sW2[i] = W2[i];
    __syncthreads();
    int n = blockIdx.x * blockDim.x + threadIdx.x;
    if (n >= nN) return;
    float inv = 1.0f / fmaxf(deg[n], 1.0f);
    float a[IN_F];
    float* row = acc1 + (size_t)n * IN_F;
#pragma unroll
    for (int i = 0; i < IN_F; ++i) a[i] = row[i] * inv;
    float g0 = 0.f, g1 = 0.f, g2 = 0.f;
#pragma unroll
    for (int j = 0; j < HID_F; ++j) {
        float t = sb1[j];
#pragma unroll
        for (int i = 0; i < IN_F; ++i) t = fmaf(a[i], sW1[i * HID_F + j], t);
        t = fmaxf(t, 0.0f);
        g0 = fmaf(t, sW2[j * OUT_F + 0], g0);
        g1 = fmaf(t, sW2[j * OUT_F + 1], g1);
        g2 = fmaf(t, sW2[j * OUT_F + 2], g2);
    }
    row[0] = g0; row[1] = g1; row[2] = g2;
}

__global__ void scatter2(const int* __restrict__ src, const int* __restrict__ dst,
                         const float* __restrict__ g, float* __restrict__ acc2, int nE) {
    int e = blockIdx.x * blockDim.x + threadIdx.x;
    if (e >= nE) return;
    int s = src[e], d = dst[e];
    const float* gs = g + (size_t)s * IN_F;
    float* a = acc2 + (size_t)d * OUT_F;
    float2 g01 = *reinterpret_cast<const float2*>(gs);
    atomicAdd(a + 0, g01.x); atomicAdd(a + 1, g01.y); atomicAdd(a + 2, gs[2]);
}

__global__ void finalize(const float* __restrict__ acc2, const float* __restrict__ deg,
                         const float* __restrict__ b2, float* __restrict__ out, int nN) {
    int n = blockIdx.x * blockDim.x + threadIdx.x;
    if (n >= nN) return;
    float inv = 1.0f / fmaxf(deg[n], 1.0f);
    out[(size_t)n * OUT_F + 0] = acc2[(size_t)n * OUT_F + 0] * inv + b2[0];
    out[(size_t)n * OUT_F + 1] = acc2[(size_t)n * OUT_F + 1] * inv + b2[1];
    out[(size_t)n * OUT_F + 2] = acc2[(size_t)n * OUT_F + 2] * inv + b2[2];
}

// ============================================================================
extern "C" void kernel_launch(void* const* d_in, const int* in_sizes, int n_in,
                              void* d_out, int out_size, void* d_ws, size_t ws_size,
                              hipStream_t stream) {
    const float* feat = (const float*)d_in[0];
    const int*   src  = (const int*)d_in[1];
    const int*   dst  = (const int*)d_in[2];
    const float* W1   = (const float*)d_in[3];
    const float* b1   = (const float*)d_in[4];
    const float* W2   = (const float*)d_in[5];
    const float* b2   = (const float*)d_in[6];
    float* out = (float*)d_out;

    const int nN = in_sizes[0] / IN_F;   // 100000
    const int nE = in_sizes[1];          // 3200000

    int nB = (nN + NPB - 1) >> NPB_SHIFT;  // 391
    int nC = (nE + CHUNK - 1) / CHUNK;     // 391

    // ws layout: g4 float4[nN] | offv int[nN] | cntv int[nN]
    //          | cursor int[nB] | packed u32[nB*CAPB] (sorted in place -> csr)
    size_t off_g4     = 0;
    size_t off_offv   = off_g4 + (size_t)nN * sizeof(float4);
    size_t off_cntv   = off_offv + (size_t)nN * sizeof(int);
    size_t off_cursor = off_cntv + (size_t)nN * sizeof(int);
    size_t off_packed = (off_cursor + (size_t)nB * sizeof(int) + 255) & ~(size_t)255;
    size_t need_fast  = off_packed + (size_t)nB * CAPB * sizeof(unsigned);

    bool fast = (ws_size >= need_fast) &&
                (nN <= (int)(SRC_MASK + 1)) &&
                (nB <= NBMAX) &&
                (nE / nB <= CAPB - 1500);   // mean + ~17 sigma headroom

    if (fast) {
        float4*   g4     = (float4*)((char*)d_ws + off_g4);
        int*      offv   = (int*)((char*)d_ws + off_offv);
        int*      cntv   = (int*)((char*)d_ws + off_cntv);
        int*      cursor = (int*)((char*)d_ws + off_cursor);
        unsigned* packed = (unsigned*)((char*)d_ws + off_packed);

        k_zero<<<1, 512, 0, stream>>>(cursor, nB);
        k_scatter<<<nC, 1024, 0, stream>>>(src, dst, nB, cursor, packed, nE);
        k_sl1<<<nB, 1024, 0, stream>>>(packed, cursor, feat, W1, b1, W2,
                                       g4, offv, cntv, nN);
        k_l2<<<(nN + 255) / 256, 256, 0, stream>>>(packed, offv, cntv, g4, b2, out, nN);
    } else {
        // fallback: atomic-scatter path (needs 10N floats)
        float* deg  = (float*)d_ws;
        float* acc1 = deg + nN;
        float* acc2 = acc1 + (size_t)nN * IN_F;
        const int TB = 256;
        int eblocks = (nE + TB - 1) / TB;
        int nblocks = (nN + TB - 1) / TB;
        hipMemsetAsync(d_ws, 0, (size_t)nN * 10 * sizeof(float), stream);
        scatter1<<<eblocks, TB, 0, stream>>>(src, dst, feat, acc1, deg, nE);
        node_mlp<<<nblocks, TB, 0, stream>>>(acc1, deg, W1, b1, W2, nN);
        scatter2<<<eblocks, TB, 0, stream>>>(src, dst, acc1, acc2, nE);
        finalize<<<nblocks, TB, 0, stream>>>(acc2, deg, b2, out, nN);
    }
}